// Round 8
// baseline (317.267 us; speedup 1.0000x reference)
//
#include <hip/hip_runtime.h>
#include <hip/hip_bf16.h>

#define BB 4
#define CC 256
#define NN 4096
#define BBNN (BB * NN)
#define NGROUPS 32
#define CPG 8
#define EPSG 1e-6f
#define QKSCL 0.30028063f             // sqrt(C^-0.5 * log2(e)) folded into q and k
#define KSPLIT 4
#define JITERS (NN / KSPLIT / 64)     // 16

typedef __bf16 bf16x8 __attribute__((ext_vector_type(8)));
typedef float  f32x4  __attribute__((ext_vector_type(4)));

typedef __attribute__((address_space(1))) const void g_void;
typedef __attribute__((address_space(3))) void l_void;

__device__ __forceinline__ unsigned short f2bf(float f) {
  unsigned u = __builtin_bit_cast(unsigned, f);
  u += 0x7fffu + ((u >> 16) & 1u);
  return (unsigned short)(u >> 16);
}
__device__ __forceinline__ float bf2f(unsigned short s) {
  return __builtin_bit_cast(float, (unsigned)s << 16);
}

__device__ __forceinline__ f32x4 mfma16(bf16x8 a, bf16x8 b, f32x4 c) {
  return __builtin_amdgcn_mfma_f32_16x16x32_bf16(a, b, c, 0, 0, 0);
}
__device__ __forceinline__ f32x4 mfma8(long a, long b, f32x4 c) {
  return __builtin_amdgcn_mfma_f32_16x16x32_fp8_fp8(a, b, c, 0, 0, 0);
}

__device__ __forceinline__ bf16x8 ldfrag(const unsigned short* p) {
  return __builtin_bit_cast(bf16x8, *(const uint4*)p);
}

// ---- fused: weights fp32->bf16 (blocks 0..255) + GroupNorm stats (256..511) ----
__global__ __launch_bounds__(256) void pre(const float* __restrict__ wq,
    const float* __restrict__ wk, const float* __restrict__ wv,
    const float* __restrict__ wo, const float* __restrict__ x,
    unsigned short* __restrict__ wbf, float* __restrict__ part) {
  if (blockIdx.x < 256) {
    int mat = blockIdx.x >> 6, blk = blockIdx.x & 63;
    const float* s = mat == 0 ? wq : mat == 1 ? wk : mat == 2 ? wv : wo;
    int i = (blk * 256 + threadIdx.x) * 4;
    float4 v = *(const float4*)&s[i];
    unsigned short* d = wbf + (size_t)mat * CC * CC + i;
    d[0] = f2bf(v.x); d[1] = f2bf(v.y); d[2] = f2bf(v.z); d[3] = f2bf(v.w);
    return;
  }
  int bx = blockIdx.x - 256;
  int pair = bx >> 1, h = bx & 1;
  const float* xp = x + (size_t)pair * (CPG * NN) + (size_t)h * (CPG * NN / 2);
  float s = 0.f, s2 = 0.f;
  for (int i = threadIdx.x; i < CPG * NN / 8; i += 256) {
    float4 v = ((const float4*)xp)[i];
    s += v.x + v.y + v.z + v.w;
    s2 += v.x * v.x + v.y * v.y + v.z * v.z + v.w * v.w;
  }
  for (int o = 32; o; o >>= 1) { s += __shfl_down(s, o); s2 += __shfl_down(s2, o); }
  __shared__ float rs[4], rs2[4];
  int wid = threadIdx.x >> 6, lane = threadIdx.x & 63;
  if (lane == 0) { rs[wid] = s; rs2[wid] = s2; }
  __syncthreads();
  if (threadIdx.x == 0) {
    part[bx * 2 + 0] = rs[0] + rs[1] + rs[2] + rs[3];
    part[bx * 2 + 1] = rs2[0] + rs2[1] + rs2[2] + rs2[3];
  }
}

// ---- GroupNorm apply -> xnT [b][n][c] bf16 ----
__global__ __launch_bounds__(256) void gn_apply(const float* __restrict__ x,
    const float* __restrict__ gw, const float* __restrict__ gb,
    const float* __restrict__ part, unsigned short* __restrict__ xnT) {
  int pair = blockIdx.x >> 2, qd = blockIdx.x & 3;
  int b = pair >> 5, g = pair & 31;
  float s = part[pair * 4 + 0] + part[pair * 4 + 2];
  float s2 = part[pair * 4 + 1] + part[pair * 4 + 3];
  float mean = s / (CPG * NN);
  float inv = rsqrtf(s2 / (CPG * NN) - mean * mean + EPSG);
  const float* xp = x + (size_t)pair * (CPG * NN);
  int n0 = qd * 1024 + threadIdx.x * 4;
  float sc[8], bi[8];
#pragma unroll
  for (int c = 0; c < 8; ++c) {
    float w = gw[g * 8 + c];
    sc[c] = inv * w;
    bi[c] = gb[g * 8 + c] - mean * inv * w;
  }
  unsigned short row[4][8];
#pragma unroll
  for (int c = 0; c < 8; ++c) {
    float4 v = *(const float4*)&xp[(size_t)c * NN + n0];
    row[0][c] = f2bf(v.x * sc[c] + bi[c]);
    row[1][c] = f2bf(v.y * sc[c] + bi[c]);
    row[2][c] = f2bf(v.z * sc[c] + bi[c]);
    row[3][c] = f2bf(v.w * sc[c] + bi[c]);
  }
#pragma unroll
  for (int r = 0; r < 4; ++r)
    *(uint4*)&xnT[((size_t)b * NN + n0 + r) * CC + g * 8] = *(const uint4*)&row[r][0];
}

// ---- QKV, 3-way mode split: q8/k8 [b][n][c] (pre-scaled), v8 [b][c][n''] ----
// grid 768 = 3 modes x 4 b x 64 ntiles; low3 XCD-pins K/V to the consumer
// attn group's XCD.
__global__ __launch_bounds__(256) void qkv(const unsigned short* __restrict__ xnT,
    const unsigned short* __restrict__ wbf,
    const float* __restrict__ bq, const float* __restrict__ bk,
    const float* __restrict__ bv,
    unsigned char* __restrict__ q8, unsigned char* __restrict__ k8,
    unsigned char* __restrict__ v8) {
  const int low = blockIdx.x & 7;
  const int b = low & 3, shalf = low >> 2;
  const int t = blockIdx.x >> 3;
  const int mode = t >> 5;              // 0=q, 1=k, 2=v
  const int u = t & 31;
  const int sidx = (u >> 4) * 2 + shalf;
  const int nt = sidx * 16 + (u & 15);
  const int n0 = nt * 64;
  __shared__ unsigned short Xs[64][CC + 8];
  int tid = threadIdx.x;
#pragma unroll
  for (int i = 0; i < 8; ++i) {
    int id = tid + 256 * i;
    int r = id >> 5, ck = id & 31;
    *(uint4*)&Xs[r][ck * 8] = *(const uint4*)&xnT[((size_t)b * NN + n0 + r) * CC + ck * 8];
  }
  __syncthreads();
  int w = tid >> 6, lane = tid & 63;
  int m = lane & 15, q4 = lane >> 4;
  if (mode < 2) {
    bf16x8 xa[8];
#pragma unroll
    for (int k = 0; k < 8; ++k)
      xa[k] = ldfrag(&Xs[w * 16 + m][k * 32 + q4 * 8]);
    const unsigned short* W = wbf + (size_t)mode * CC * CC;
    const float* bias = mode ? bk : bq;
    unsigned char* dst = mode ? k8 : q8;
    for (int ot = 0; ot < 16; ++ot) {
      f32x4 acc = {0.f, 0.f, 0.f, 0.f};
#pragma unroll
      for (int k = 0; k < 8; ++k) {
        bf16x8 bf = ldfrag(&W[(size_t)(ot * 16 + m) * CC + k * 32 + q4 * 8]);
        acc = mfma16(xa[k], bf, acc);
      }
      int o = ot * 16 + m;
      float bia = bias[o];
      unsigned pk01 = __builtin_amdgcn_cvt_pk_fp8_f32(
          (acc[0] + bia) * QKSCL, (acc[1] + bia) * QKSCL, 0u, false);
      unsigned pk23 = __builtin_amdgcn_cvt_pk_fp8_f32(
          (acc[2] + bia) * QKSCL, (acc[3] + bia) * QKSCL, 0u, false);
      size_t base = ((size_t)b * NN + n0 + w * 16 + q4 * 4) * CC + o;
      dst[base]          = (unsigned char)(pk01 & 0xff);
      dst[base + CC]     = (unsigned char)((pk01 >> 8) & 0xff);
      dst[base + 2 * CC] = (unsigned char)(pk23 & 0xff);
      dst[base + 3 * CC] = (unsigned char)((pk23 >> 8) & 0xff);
    }
  } else {
    const unsigned short* Wv = wbf + 2 * CC * CC;
    for (int ot = 0; ot < 4; ++ot) {
      int o0 = w * 64 + ot * 16;
      bf16x8 af[8];
#pragma unroll
      for (int k = 0; k < 8; ++k)
        af[k] = ldfrag(&Wv[(size_t)(o0 + m) * CC + k * 32 + q4 * 8]);
#pragma unroll
      for (int nt4 = 0; nt4 < 4; ++nt4) {
        f32x4 acc = {0.f, 0.f, 0.f, 0.f};
#pragma unroll
        for (int k = 0; k < 8; ++k) {
          bf16x8 bfr = ldfrag(&Xs[nt4 * 16 + m][k * 32 + q4 * 8]);
          acc = mfma16(af[k], bfr, acc);
        }
        // K-dim permutation within the 64-block: j -> j''
        int j = nt4 * 16 + m;
        int jp = (j & 0x23) | ((j & 0x0C) << 1) | ((j & 0x10) >> 2);
        int n = n0 + jp;
        int o = o0 + q4 * 4;
        unsigned pk01 = __builtin_amdgcn_cvt_pk_fp8_f32(acc[0] + bv[o], acc[1] + bv[o + 1], 0u, false);
        unsigned pk23 = __builtin_amdgcn_cvt_pk_fp8_f32(acc[2] + bv[o + 2], acc[3] + bv[o + 3], 0u, false);
        size_t base = ((size_t)b * CC + o) * NN + n;
        v8[base]          = (unsigned char)(pk01 & 0xff);
        v8[base + NN]     = (unsigned char)((pk01 >> 8) & 0xff);
        v8[base + 2 * NN] = (unsigned char)(pk23 & 0xff);
        v8[base + 3 * NN] = (unsigned char)((pk23 >> 8) & 0xff);
      }
    }
  }
}

// DMA one 64-j fp8 tile with 512 threads: K 64x256B (granule XOR (j>>1)&7),
// V 256x64B (granule XOR c&3). item = const + tid -> LDS dest is
// wave-uniform + lane*16 as required by global_load_lds.
__device__ __forceinline__ void stage8(const unsigned char* __restrict__ kp,
    const unsigned char* __restrict__ vp, int j0,
    unsigned char* Kb, unsigned char* Vb, int tid) {
#pragma unroll
  for (int t = 0; t < 2; ++t) {
    int item = t * 512 + tid;
    int row = item >> 4, d16 = item & 15;
    int s16 = d16 ^ ((row >> 1) & 7);
    const unsigned char* g = kp + (size_t)(j0 + row) * CC + s16 * 16;
    __builtin_amdgcn_global_load_lds((g_void*)g, (l_void*)(Kb + item * 16), 16, 0, 0);
  }
#pragma unroll
  for (int t = 0; t < 2; ++t) {
    int item = t * 512 + tid;
    int row = item >> 2, gl = item & 3;
    int gg = gl ^ (row & 3);
    const unsigned char* g = vp + (size_t)row * NN + j0 + gg * 16;
    __builtin_amdgcn_global_load_lds((g_void*)g, (l_void*)(Vb + item * 16), 16, 0, 0);
  }
}

// ---- flash attention, S^T form: grid 512 = 16 (s,b) x 32 itiles, 512 thr ----
// 8 waves x 16 i-rows = 128-i block; 2 blocks/CU = 16 waves/CU.
__global__ __launch_bounds__(512, 4) void attn(const unsigned char* __restrict__ q8,
    const unsigned char* __restrict__ k8, const unsigned char* __restrict__ v8,
    unsigned short* __restrict__ accP, float* __restrict__ mlP) {
  const int grp = blockIdx.x & 15;
  const int s = grp >> 2, b = grp & 3;
  const int it = blockIdx.x >> 4;
  const int i0 = it * 128;
  __shared__ __align__(16) unsigned char pool[65536];
  unsigned char* Kd0 = pool;
  unsigned char* Kd1 = pool + 16384;
  unsigned char* Vd0 = pool + 32768;
  unsigned char* Vd1 = pool + 49152;
  int tid = threadIdx.x, w = tid >> 6, lane = tid & 63;
  int m = lane & 15, q4 = lane >> 4;
  int q4h = q4 >> 1, q4l = q4 & 1;
  const unsigned char* kp = k8 + (size_t)b * NN * CC;
  const unsigned char* vp = v8 + (size_t)b * CC * NN;
  long qa[8];
#pragma unroll
  for (int kc = 0; kc < 8; ++kc)
    qa[kc] = *(const long*)&q8[((size_t)b * NN + i0 + w * 16 + m) * CC + kc * 32 + q4 * 8];
  f32x4 acc[16];
#pragma unroll
  for (int i = 0; i < 16; ++i) acc[i] = (f32x4){0.f, 0.f, 0.f, 0.f};
  float mrow = -1e30f, lrow = 0.f;
  const int jbase = s * (NN / KSPLIT);
  stage8(kp, vp, jbase, Kd0, Vd0, tid);
  for (int jt = 0; jt < JITERS; ++jt) {
    __syncthreads();               // DMA(buf) drained; all waves done with buf^1
    if (jt + 1 < JITERS)
      stage8(kp, vp, jbase + (jt + 1) * 64,
             (jt & 1) ? Kd0 : Kd1, (jt & 1) ? Vd0 : Vd1, tid);
    const unsigned char* Ks = (jt & 1) ? Kd1 : Kd0;
    const unsigned char* Vs = (jt & 1) ? Vd1 : Vd0;
    f32x4 sv[4];
#pragma unroll
    for (int jt4 = 0; jt4 < 4; ++jt4) {
      f32x4 a = {0.f, 0.f, 0.f, 0.f};
#pragma unroll
      for (int kc = 0; kc < 8; ++kc) {
        int gl = (kc * 2 + q4h) ^ ((m >> 1) & 7);
        long kf = *(const long*)&Ks[(jt4 * 16 + m) * 256 + gl * 16 + q4l * 8];
        a = mfma8(kf, qa[kc], a);
      }
      sv[jt4] = a;
    }
    float mx = fmaxf(fmaxf(fmaxf(sv[0][0], sv[0][1]), fmaxf(sv[0][2], sv[0][3])),
                     fmaxf(fmaxf(sv[1][0], sv[1][1]), fmaxf(sv[1][2], sv[1][3])));
    mx = fmaxf(mx, fmaxf(fmaxf(fmaxf(sv[2][0], sv[2][1]), fmaxf(sv[2][2], sv[2][3])),
                         fmaxf(fmaxf(sv[3][0], sv[3][1]), fmaxf(sv[3][2], sv[3][3]))));
    mx = fmaxf(mx, __shfl_xor(mx, 16));
    mx = fmaxf(mx, __shfl_xor(mx, 32));
    float mnew = fmaxf(mrow, mx);
    float alpha = exp2f(mrow - mnew);
    mrow = mnew;
    float rsum = 0.f;
    unsigned pd[4];
#pragma unroll
    for (int jt4 = 0; jt4 < 4; ++jt4) {
      float e0 = exp2f(sv[jt4][0] - mnew);
      float e1 = exp2f(sv[jt4][1] - mnew);
      float e2 = exp2f(sv[jt4][2] - mnew);
      float e3 = exp2f(sv[jt4][3] - mnew);
      rsum += (e0 + e1) + (e2 + e3);
      unsigned d = __builtin_amdgcn_cvt_pk_fp8_f32(e0, e1, 0u, false);
      pd[jt4] = __builtin_amdgcn_cvt_pk_fp8_f32(e2, e3, d, true);
    }
    rsum += __shfl_xor(rsum, 16);
    rsum += __shfl_xor(rsum, 32);
    lrow = lrow * alpha + rsum;
    if (__any(alpha != 1.0f)) {
#pragma unroll
      for (int ct = 0; ct < 16; ++ct) acc[ct] *= alpha;
    }
    int voff = ((q4h) ^ (m & 3)) * 16 + q4l * 8;          // p=0
    int voff1 = ((2 + q4h) ^ (m & 3)) * 16 + q4l * 8;     // p=1
#pragma unroll
    for (int p = 0; p < 2; ++p) {
      uint2 pu = {pd[2 * p], pd[2 * p + 1]};
      long pT = __builtin_bit_cast(long, pu);
      int vo = p ? voff1 : voff;
#pragma unroll
      for (int ct = 0; ct < 16; ++ct) {
        long vf = *(const long*)&Vs[(ct * 16 + m) * 64 + vo];
        acc[ct] = mfma8(vf, pT, acc[ct]);
      }
    }
  }
  // epilogue: per-lane (i = m) stats; O^T -> 2-pass LDS transpose -> store
  size_t rq = (size_t)(s * BB + b) * NN + i0 + w * 16 + m;
  if (q4 == 0) {
    mlP[rq * 2 + 0] = mrow;
    mlP[rq * 2 + 1] = lrow;
  }
  unsigned short* tp = (unsigned short*)pool;   // 64 rows x 260 shorts
#pragma unroll
  for (int pass = 0; pass < 2; ++pass) {
    __syncthreads();
    if ((w >> 2) == pass) {
      int wl = w & 3;
#pragma unroll
      for (int ct = 0; ct < 16; ++ct) {
        unsigned lo = f2bf(acc[ct][0]) | ((unsigned)f2bf(acc[ct][1]) << 16);
        unsigned hi = f2bf(acc[ct][2]) | ((unsigned)f2bf(acc[ct][3]) << 16);
        uint2 pk = {lo, hi};
        *(uint2*)&tp[(wl * 16 + m) * 260 + ct * 16 + q4 * 4] = pk;
      }
    }
    __syncthreads();
#pragma unroll
    for (int u = 0; u < 4; ++u) {
      int id = u * 512 + tid;
      int row = id >> 5, ck = id & 31;
      uint4 v = *(const uint4*)&tp[row * 260 + ck * 8];
      *(uint4*)&accP[((size_t)(s * BB + b) * NN + i0 + pass * 64 + row) * CC + ck * 8] = v;
    }
  }
}

// ---- output projection + combine partials + bias + residual; grid 512 ----
__global__ __launch_bounds__(256) void proj(const unsigned short* __restrict__ accP,
    const float* __restrict__ mlP, const unsigned short* __restrict__ Wo,
    const float* __restrict__ bo, const float* __restrict__ x,
    float* __restrict__ out) {
  const int b = blockIdx.x >> 7, nt = blockIdx.x & 127;
  const int n0 = nt * 32;
  __shared__ unsigned short As[32][CC + 8];
  __shared__ float wr[KSPLIT][36];
  int tid = threadIdx.x;
  if (tid < 32) {
    int n = n0 + tid;
    float mv[KSPLIT], lv[KSPLIT], M = -1e30f;
#pragma unroll
    for (int s = 0; s < KSPLIT; ++s) {
      size_t rq = (size_t)(s * BB + b) * NN + n;
      mv[s] = mlP[rq * 2];
      lv[s] = mlP[rq * 2 + 1];
      M = fmaxf(M, mv[s]);
    }
    float ws[KSPLIT], d = 0.f;
#pragma unroll
    for (int s = 0; s < KSPLIT; ++s) {
      ws[s] = exp2f(mv[s] - M);
      d += lv[s] * ws[s];
    }
    float inv = 1.f / d;
#pragma unroll
    for (int s = 0; s < KSPLIT; ++s) wr[s][tid] = ws[s] * inv;
  }
  __syncthreads();
#pragma unroll
  for (int i = 0; i < 4; ++i) {
    int id = tid + 256 * i;
    int r = id >> 5, ck = id & 31;
    int n = n0 + r;
    float f[8] = {0.f, 0.f, 0.f, 0.f, 0.f, 0.f, 0.f, 0.f};
#pragma unroll
    for (int s = 0; s < KSPLIT; ++s) {
      uint4 a = *(const uint4*)&accP[((size_t)(s * BB + b) * NN + n) * CC + ck * 8];
      const unsigned* p = (const unsigned*)&a;
      float wgt = wr[s][r];
#pragma unroll
      for (int k = 0; k < 4; ++k) {
        f[k * 2 + 0] += bf2f((unsigned short)(p[k] & 0xffff)) * wgt;
        f[k * 2 + 1] += bf2f((unsigned short)(p[k] >> 16)) * wgt;
      }
    }
    unsigned short ov[8];
#pragma unroll
    for (int k = 0; k < 8; ++k) ov[k] = f2bf(f[k]);
    *(uint4*)&As[r][ck * 8] = *(const uint4*)&ov[0];
  }
  __syncthreads();
  int w = tid >> 6, lane = tid & 63, m = lane & 15, q4 = lane >> 4;
  for (int ot = 0; ot < 4; ++ot) {
    int o0 = w * 64 + ot * 16;
    bf16x8 af[8];
#pragma unroll
    for (int k = 0; k < 8; ++k)
      af[k] = ldfrag(&Wo[(size_t)(o0 + m) * CC + k * 32 + q4 * 8]);
#pragma unroll
    for (int nt4 = 0; nt4 < 2; ++nt4) {
      f32x4 a = {0.f, 0.f, 0.f, 0.f};
#pragma unroll
      for (int k = 0; k < 8; ++k) {
        bf16x8 bf = ldfrag(&As[nt4 * 16 + m][k * 32 + q4 * 8]);
        a = mfma16(af[k], bf, a);
      }
      int n = n0 + nt4 * 16 + m;
#pragma unroll
      for (int r = 0; r < 4; ++r) {
        int o = o0 + q4 * 4 + r;
        size_t idx = ((size_t)b * CC + o) * NN + n;
        out[idx] = x[idx] + bo[o] + a[r];
      }
    }
  }
}

extern "C" void kernel_launch(void* const* d_in, const int* in_sizes, int n_in,
                              void* d_out, int out_size, void* d_ws, size_t ws_size,
                              hipStream_t stream) {
  const float* x  = (const float*)d_in[0];
  const float* gw = (const float*)d_in[1];
  const float* gb = (const float*)d_in[2];
  const float* wq = (const float*)d_in[3];
  const float* bq = (const float*)d_in[4];
  const float* wk = (const float*)d_in[5];
  const float* bk = (const float*)d_in[6];
  const float* wv = (const float*)d_in[7];
  const float* bv = (const float*)d_in[8];
  const float* wo = (const float*)d_in[9];
  const float* bo = (const float*)d_in[10];

  const size_t M4 = (size_t)BB * NN * CC;
  unsigned short* xnT = (unsigned short*)d_ws;
  unsigned short* wbf = xnT + M4;                       // 4*65536 bf16
  unsigned short* accPb = wbf + 4 * CC * CC;            // KSPLIT*M4 bf16
  float* mlP  = (float*)(accPb + (size_t)KSPLIT * M4);  // KSPLIT*BBNN*2 f32
  float* part = mlP + (size_t)KSPLIT * BBNN * 2;        // 512 f32
  unsigned char* q8 = (unsigned char*)(part + 512);
  unsigned char* k8 = q8 + M4;
  unsigned char* v8 = k8 + M4;

  pre<<<512, 256, 0, stream>>>(wq, wk, wv, wo, x, wbf, part);
  gn_apply<<<512, 256, 0, stream>>>(x, gw, gb, part, xnT);
  qkv<<<768, 256, 0, stream>>>(xnT, wbf, bq, bk, bv, q8, k8, v8);
  attn<<<KSPLIT * BB * 32, 512, 0, stream>>>(q8, k8, v8, accPb, mlP);
  proj<<<512, 256, 0, stream>>>(accPb, mlP, wbf + 3 * CC * CC, bo, x, (float*)d_out);
}

// Round 9
// 267.779 us; speedup vs baseline: 1.1848x; 1.1848x over previous
//
#include <hip/hip_runtime.h>
#include <hip/hip_bf16.h>

#define BB 4
#define CC 256
#define NN 4096
#define BBNN (BB * NN)
#define NGROUPS 32
#define CPG 8
#define EPSG 1e-6f
#define QKSCL 0.30028063f             // sqrt(C^-0.5 * log2(e)) folded into q and k
#define KSPLIT 4
#define JITERS (NN / KSPLIT / 64)     // 16

typedef __bf16 bf16x8 __attribute__((ext_vector_type(8)));
typedef float  f32x4  __attribute__((ext_vector_type(4)));

typedef __attribute__((address_space(1))) const void g_void;
typedef __attribute__((address_space(3))) void l_void;

__device__ __forceinline__ unsigned short f2bf(float f) {
  unsigned u = __builtin_bit_cast(unsigned, f);
  u += 0x7fffu + ((u >> 16) & 1u);
  return (unsigned short)(u >> 16);
}
__device__ __forceinline__ float bf2f(unsigned short s) {
  return __builtin_bit_cast(float, (unsigned)s << 16);
}

__device__ __forceinline__ f32x4 mfma16(bf16x8 a, bf16x8 b, f32x4 c) {
  return __builtin_amdgcn_mfma_f32_16x16x32_bf16(a, b, c, 0, 0, 0);
}
__device__ __forceinline__ f32x4 mfma8(long a, long b, f32x4 c) {
  return __builtin_amdgcn_mfma_f32_16x16x32_fp8_fp8(a, b, c, 0, 0, 0);
}

__device__ __forceinline__ bf16x8 ldfrag(const unsigned short* p) {
  return __builtin_bit_cast(bf16x8, *(const uint4*)p);
}

// ---- fused: weights fp32->bf16 (blocks 0..255) + GroupNorm stats (256..511) ----
__global__ __launch_bounds__(256) void pre(const float* __restrict__ wq,
    const float* __restrict__ wk, const float* __restrict__ wv,
    const float* __restrict__ wo, const float* __restrict__ x,
    unsigned short* __restrict__ wbf, float* __restrict__ part) {
  if (blockIdx.x < 256) {
    int mat = blockIdx.x >> 6, blk = blockIdx.x & 63;
    const float* s = mat == 0 ? wq : mat == 1 ? wk : mat == 2 ? wv : wo;
    int i = (blk * 256 + threadIdx.x) * 4;
    float4 v = *(const float4*)&s[i];
    unsigned short* d = wbf + (size_t)mat * CC * CC + i;
    d[0] = f2bf(v.x); d[1] = f2bf(v.y); d[2] = f2bf(v.z); d[3] = f2bf(v.w);
    return;
  }
  int bx = blockIdx.x - 256;
  int pair = bx >> 1, h = bx & 1;
  const float* xp = x + (size_t)pair * (CPG * NN) + (size_t)h * (CPG * NN / 2);
  float s = 0.f, s2 = 0.f;
  for (int i = threadIdx.x; i < CPG * NN / 8; i += 256) {
    float4 v = ((const float4*)xp)[i];
    s += v.x + v.y + v.z + v.w;
    s2 += v.x * v.x + v.y * v.y + v.z * v.z + v.w * v.w;
  }
  for (int o = 32; o; o >>= 1) { s += __shfl_down(s, o); s2 += __shfl_down(s2, o); }
  __shared__ float rs[4], rs2[4];
  int wid = threadIdx.x >> 6, lane = threadIdx.x & 63;
  if (lane == 0) { rs[wid] = s; rs2[wid] = s2; }
  __syncthreads();
  if (threadIdx.x == 0) {
    part[bx * 2 + 0] = rs[0] + rs[1] + rs[2] + rs[3];
    part[bx * 2 + 1] = rs2[0] + rs2[1] + rs2[2] + rs2[3];
  }
}

// ---- GroupNorm apply -> xnT [b][n][c] bf16 ----
__global__ __launch_bounds__(256) void gn_apply(const float* __restrict__ x,
    const float* __restrict__ gw, const float* __restrict__ gb,
    const float* __restrict__ part, unsigned short* __restrict__ xnT) {
  int pair = blockIdx.x >> 2, qd = blockIdx.x & 3;
  int b = pair >> 5, g = pair & 31;
  float s = part[pair * 4 + 0] + part[pair * 4 + 2];
  float s2 = part[pair * 4 + 1] + part[pair * 4 + 3];
  float mean = s / (CPG * NN);
  float inv = rsqrtf(s2 / (CPG * NN) - mean * mean + EPSG);
  const float* xp = x + (size_t)pair * (CPG * NN);
  int n0 = qd * 1024 + threadIdx.x * 4;
  float sc[8], bi[8];
#pragma unroll
  for (int c = 0; c < 8; ++c) {
    float w = gw[g * 8 + c];
    sc[c] = inv * w;
    bi[c] = gb[g * 8 + c] - mean * inv * w;
  }
  unsigned short row[4][8];
#pragma unroll
  for (int c = 0; c < 8; ++c) {
    float4 v = *(const float4*)&xp[(size_t)c * NN + n0];
    row[0][c] = f2bf(v.x * sc[c] + bi[c]);
    row[1][c] = f2bf(v.y * sc[c] + bi[c]);
    row[2][c] = f2bf(v.z * sc[c] + bi[c]);
    row[3][c] = f2bf(v.w * sc[c] + bi[c]);
  }
#pragma unroll
  for (int r = 0; r < 4; ++r)
    *(uint4*)&xnT[((size_t)b * NN + n0 + r) * CC + g * 8] = *(const uint4*)&row[r][0];
}

// ---- QKV, 3-way mode split: q8/k8 [b][n][c] (pre-scaled), v8 [b][c][n''] ----
__global__ __launch_bounds__(256) void qkv(const unsigned short* __restrict__ xnT,
    const unsigned short* __restrict__ wbf,
    const float* __restrict__ bq, const float* __restrict__ bk,
    const float* __restrict__ bv,
    unsigned char* __restrict__ q8, unsigned char* __restrict__ k8,
    unsigned char* __restrict__ v8) {
  const int low = blockIdx.x & 7;
  const int b = low & 3, shalf = low >> 2;
  const int t = blockIdx.x >> 3;
  const int mode = t >> 5;              // 0=q, 1=k, 2=v
  const int u = t & 31;
  const int sidx = (u >> 4) * 2 + shalf;
  const int nt = sidx * 16 + (u & 15);
  const int n0 = nt * 64;
  __shared__ unsigned short Xs[64][CC + 8];
  int tid = threadIdx.x;
#pragma unroll
  for (int i = 0; i < 8; ++i) {
    int id = tid + 256 * i;
    int r = id >> 5, ck = id & 31;
    *(uint4*)&Xs[r][ck * 8] = *(const uint4*)&xnT[((size_t)b * NN + n0 + r) * CC + ck * 8];
  }
  __syncthreads();
  int w = tid >> 6, lane = tid & 63;
  int m = lane & 15, q4 = lane >> 4;
  if (mode < 2) {
    bf16x8 xa[8];
#pragma unroll
    for (int k = 0; k < 8; ++k)
      xa[k] = ldfrag(&Xs[w * 16 + m][k * 32 + q4 * 8]);
    const unsigned short* W = wbf + (size_t)mode * CC * CC;
    const float* bias = mode ? bk : bq;
    unsigned char* dst = mode ? k8 : q8;
    for (int ot = 0; ot < 16; ++ot) {
      f32x4 acc = {0.f, 0.f, 0.f, 0.f};
#pragma unroll
      for (int k = 0; k < 8; ++k) {
        bf16x8 bf = ldfrag(&W[(size_t)(ot * 16 + m) * CC + k * 32 + q4 * 8]);
        acc = mfma16(xa[k], bf, acc);
      }
      int o = ot * 16 + m;
      float bia = bias[o];
      unsigned pk01 = __builtin_amdgcn_cvt_pk_fp8_f32(
          (acc[0] + bia) * QKSCL, (acc[1] + bia) * QKSCL, 0u, false);
      unsigned pk23 = __builtin_amdgcn_cvt_pk_fp8_f32(
          (acc[2] + bia) * QKSCL, (acc[3] + bia) * QKSCL, 0u, false);
      size_t base = ((size_t)b * NN + n0 + w * 16 + q4 * 4) * CC + o;
      dst[base]          = (unsigned char)(pk01 & 0xff);
      dst[base + CC]     = (unsigned char)((pk01 >> 8) & 0xff);
      dst[base + 2 * CC] = (unsigned char)(pk23 & 0xff);
      dst[base + 3 * CC] = (unsigned char)((pk23 >> 8) & 0xff);
    }
  } else {
    const unsigned short* Wv = wbf + 2 * CC * CC;
    for (int ot = 0; ot < 4; ++ot) {
      int o0 = w * 64 + ot * 16;
      bf16x8 af[8];
#pragma unroll
      for (int k = 0; k < 8; ++k)
        af[k] = ldfrag(&Wv[(size_t)(o0 + m) * CC + k * 32 + q4 * 8]);
#pragma unroll
      for (int nt4 = 0; nt4 < 4; ++nt4) {
        f32x4 acc = {0.f, 0.f, 0.f, 0.f};
#pragma unroll
        for (int k = 0; k < 8; ++k) {
          bf16x8 bfr = ldfrag(&Xs[nt4 * 16 + m][k * 32 + q4 * 8]);
          acc = mfma16(af[k], bfr, acc);
        }
        // K-dim permutation within the 64-block: j -> j''
        int j = nt4 * 16 + m;
        int jp = (j & 0x23) | ((j & 0x0C) << 1) | ((j & 0x10) >> 2);
        int n = n0 + jp;
        int o = o0 + q4 * 4;
        unsigned pk01 = __builtin_amdgcn_cvt_pk_fp8_f32(acc[0] + bv[o], acc[1] + bv[o + 1], 0u, false);
        unsigned pk23 = __builtin_amdgcn_cvt_pk_fp8_f32(acc[2] + bv[o + 2], acc[3] + bv[o + 3], 0u, false);
        size_t base = ((size_t)b * CC + o) * NN + n;
        v8[base]          = (unsigned char)(pk01 & 0xff);
        v8[base + NN]     = (unsigned char)((pk01 >> 8) & 0xff);
        v8[base + 2 * NN] = (unsigned char)(pk23 & 0xff);
        v8[base + 3 * NN] = (unsigned char)((pk23 >> 8) & 0xff);
      }
    }
  }
}

// DMA one 64-j fp8 K tile (64x256B, granule XOR (j>>1)&7), 256 threads.
__device__ __forceinline__ void stageK8(const unsigned char* __restrict__ kp,
    int j0, unsigned char* Kb, int tid) {
#pragma unroll
  for (int t = 0; t < 4; ++t) {
    int item = t * 256 + tid;
    int row = item >> 4, d16 = item & 15;
    int s16 = d16 ^ ((row >> 1) & 7);
    const unsigned char* g = kp + (size_t)(j0 + row) * CC + s16 * 16;
    __builtin_amdgcn_global_load_lds((g_void*)g, (l_void*)(Kb + item * 16), 16, 0, 0);
  }
}
// DMA one 64-j fp8 V tile (256x64B, granule XOR c&3), 256 threads.
__device__ __forceinline__ void stageV8(const unsigned char* __restrict__ vp,
    int j0, unsigned char* Vb, int tid) {
#pragma unroll
  for (int t = 0; t < 4; ++t) {
    int item = t * 256 + tid;
    int row = item >> 2, gl = item & 3;
    int gg = gl ^ (row & 3);
    const unsigned char* g = vp + (size_t)row * NN + j0 + gg * 16;
    __builtin_amdgcn_global_load_lds((g_void*)g, (l_void*)(Vb + item * 16), 16, 0, 0);
  }
}

// ---- flash attention, S^T form: grid 1024 = 16 (s,b) x 64 itiles, 256 thr ----
// LDS 48KB (K single-buffer + V double-buffer) -> 3 blocks/CU = 12 waves/CU.
// launch_bounds(256,3): reg cap 170 >= ~152 needed -> no spill (R8 lesson).
// K(jt+1) staged after the post-QK barrier, overlapping softmax+PV.
__global__ __launch_bounds__(256, 3) void attn(const unsigned char* __restrict__ q8,
    const unsigned char* __restrict__ k8, const unsigned char* __restrict__ v8,
    unsigned short* __restrict__ accP, float* __restrict__ mlP) {
  const int grp = blockIdx.x & 15;
  const int s = grp >> 2, b = grp & 3;
  const int it = blockIdx.x >> 4;
  const int i0 = it * 64;
  __shared__ __align__(16) unsigned char pool[49152];
  unsigned char* Kd  = pool;              // 16 KB, single
  unsigned char* Vd0 = pool + 16384;
  unsigned char* Vd1 = pool + 32768;
  int tid = threadIdx.x, w = tid >> 6, lane = tid & 63;
  int m = lane & 15, q4 = lane >> 4;
  int q4h = q4 >> 1, q4l = q4 & 1;
  const unsigned char* kp = k8 + (size_t)b * NN * CC;
  const unsigned char* vp = v8 + (size_t)b * CC * NN;
  long qa[8];
#pragma unroll
  for (int kc = 0; kc < 8; ++kc)
    qa[kc] = *(const long*)&q8[((size_t)b * NN + i0 + w * 16 + m) * CC + kc * 32 + q4 * 8];
  f32x4 acc[16];
#pragma unroll
  for (int i = 0; i < 16; ++i) acc[i] = (f32x4){0.f, 0.f, 0.f, 0.f};
  float mrow = -1e30f, lrow = 0.f;
  const int jbase = s * (NN / KSPLIT);
  stageK8(kp, jbase, Kd, tid);
  stageV8(vp, jbase, Vd0, tid);
  for (int jt = 0; jt < JITERS; ++jt) {
    __syncthreads();               // A: K(jt)+V(jt) DMA drained; PV(jt-1) done
    if (jt + 1 < JITERS)
      stageV8(vp, jbase + (jt + 1) * 64, (jt & 1) ? Vd0 : Vd1, tid);
    const unsigned char* Ks = Kd;
    const unsigned char* Vs = (jt & 1) ? Vd1 : Vd0;
    f32x4 sv[4];
#pragma unroll
    for (int jt4 = 0; jt4 < 4; ++jt4) {
      f32x4 a = {0.f, 0.f, 0.f, 0.f};
#pragma unroll
      for (int kc = 0; kc < 8; ++kc) {
        int gl = (kc * 2 + q4h) ^ ((m >> 1) & 7);
        long kf = *(const long*)&Ks[(jt4 * 16 + m) * 256 + gl * 16 + q4l * 8];
        a = mfma8(kf, qa[kc], a);
      }
      sv[jt4] = a;
    }
    __syncthreads();               // B: all waves done reading Kd
    if (jt + 1 < JITERS)
      stageK8(kp, jbase + (jt + 1) * 64, Kd, tid);   // overlaps softmax+PV
    float mx = fmaxf(fmaxf(fmaxf(sv[0][0], sv[0][1]), fmaxf(sv[0][2], sv[0][3])),
                     fmaxf(fmaxf(sv[1][0], sv[1][1]), fmaxf(sv[1][2], sv[1][3])));
    mx = fmaxf(mx, fmaxf(fmaxf(fmaxf(sv[2][0], sv[2][1]), fmaxf(sv[2][2], sv[2][3])),
                         fmaxf(fmaxf(sv[3][0], sv[3][1]), fmaxf(sv[3][2], sv[3][3]))));
    mx = fmaxf(mx, __shfl_xor(mx, 16));
    mx = fmaxf(mx, __shfl_xor(mx, 32));
    float mnew = fmaxf(mrow, mx);
    float alpha = exp2f(mrow - mnew);
    mrow = mnew;
    float rsum = 0.f;
    unsigned pd[4];
#pragma unroll
    for (int jt4 = 0; jt4 < 4; ++jt4) {
      float e0 = exp2f(sv[jt4][0] - mnew);
      float e1 = exp2f(sv[jt4][1] - mnew);
      float e2 = exp2f(sv[jt4][2] - mnew);
      float e3 = exp2f(sv[jt4][3] - mnew);
      rsum += (e0 + e1) + (e2 + e3);
      unsigned d = __builtin_amdgcn_cvt_pk_fp8_f32(e0, e1, 0u, false);
      pd[jt4] = __builtin_amdgcn_cvt_pk_fp8_f32(e2, e3, d, true);
    }
    rsum += __shfl_xor(rsum, 16);
    rsum += __shfl_xor(rsum, 32);
    lrow = lrow * alpha + rsum;
    if (__any(alpha != 1.0f)) {
#pragma unroll
      for (int ct = 0; ct < 16; ++ct) acc[ct] *= alpha;
    }
    int voff = ((q4h) ^ (m & 3)) * 16 + q4l * 8;          // p=0
    int voff1 = ((2 + q4h) ^ (m & 3)) * 16 + q4l * 8;     // p=1
#pragma unroll
    for (int p = 0; p < 2; ++p) {
      uint2 pu = {pd[2 * p], pd[2 * p + 1]};
      long pT = __builtin_bit_cast(long, pu);
      int vo = p ? voff1 : voff;
#pragma unroll
      for (int ct = 0; ct < 16; ++ct) {
        long vf = *(const long*)&Vs[(ct * 16 + m) * 64 + vo];
        acc[ct] = mfma8(vf, pT, acc[ct]);
      }
    }
  }
  // epilogue: per-lane (i = m) stats; O^T -> LDS transpose -> coalesced store
  size_t rq = (size_t)(s * BB + b) * NN + i0 + w * 16 + m;
  if (q4 == 0) {
    mlP[rq * 2 + 0] = mrow;
    mlP[rq * 2 + 1] = lrow;
  }
  __syncthreads();
  unsigned short* tp = (unsigned short*)pool;   // 64 rows x 260 shorts = 33.3KB
#pragma unroll
  for (int ct = 0; ct < 16; ++ct) {
    unsigned lo = f2bf(acc[ct][0]) | ((unsigned)f2bf(acc[ct][1]) << 16);
    unsigned hi = f2bf(acc[ct][2]) | ((unsigned)f2bf(acc[ct][3]) << 16);
    uint2 pk = {lo, hi};
    *(uint2*)&tp[(w * 16 + m) * 260 + ct * 16 + q4 * 4] = pk;
  }
  __syncthreads();
#pragma unroll
  for (int u = 0; u < 8; ++u) {
    int id = u * 256 + tid;
    int row = id >> 5, ck = id & 31;
    uint4 v = *(const uint4*)&tp[row * 260 + ck * 8];
    *(uint4*)&accP[((size_t)(s * BB + b) * NN + i0 + row) * CC + ck * 8] = v;
  }
}

// ---- output projection + combine partials + bias + residual; grid 512 ----
__global__ __launch_bounds__(256) void proj(const unsigned short* __restrict__ accP,
    const float* __restrict__ mlP, const unsigned short* __restrict__ Wo,
    const float* __restrict__ bo, const float* __restrict__ x,
    float* __restrict__ out) {
  const int b = blockIdx.x >> 7, nt = blockIdx.x & 127;
  const int n0 = nt * 32;
  __shared__ unsigned short As[32][CC + 8];
  __shared__ float wr[KSPLIT][36];
  int tid = threadIdx.x;
  if (tid < 32) {
    int n = n0 + tid;
    float mv[KSPLIT], lv[KSPLIT], M = -1e30f;
#pragma unroll
    for (int s = 0; s < KSPLIT; ++s) {
      size_t rq = (size_t)(s * BB + b) * NN + n;
      mv[s] = mlP[rq * 2];
      lv[s] = mlP[rq * 2 + 1];
      M = fmaxf(M, mv[s]);
    }
    float ws[KSPLIT], d = 0.f;
#pragma unroll
    for (int s = 0; s < KSPLIT; ++s) {
      ws[s] = exp2f(mv[s] - M);
      d += lv[s] * ws[s];
    }
    float inv = 1.f / d;
#pragma unroll
    for (int s = 0; s < KSPLIT; ++s) wr[s][tid] = ws[s] * inv;
  }
  __syncthreads();
#pragma unroll
  for (int i = 0; i < 4; ++i) {
    int id = tid + 256 * i;
    int r = id >> 5, ck = id & 31;
    int n = n0 + r;
    float f[8] = {0.f, 0.f, 0.f, 0.f, 0.f, 0.f, 0.f, 0.f};
#pragma unroll
    for (int s = 0; s < KSPLIT; ++s) {
      uint4 a = *(const uint4*)&accP[((size_t)(s * BB + b) * NN + n) * CC + ck * 8];
      const unsigned* p = (const unsigned*)&a;
      float wgt = wr[s][r];
#pragma unroll
      for (int k = 0; k < 4; ++k) {
        f[k * 2 + 0] += bf2f((unsigned short)(p[k] & 0xffff)) * wgt;
        f[k * 2 + 1] += bf2f((unsigned short)(p[k] >> 16)) * wgt;
      }
    }
    unsigned short ov[8];
#pragma unroll
    for (int k = 0; k < 8; ++k) ov[k] = f2bf(f[k]);
    *(uint4*)&As[r][ck * 8] = *(const uint4*)&ov[0];
  }
  __syncthreads();
  int w = tid >> 6, lane = tid & 63, m = lane & 15, q4 = lane >> 4;
  for (int ot = 0; ot < 4; ++ot) {
    int o0 = w * 64 + ot * 16;
    bf16x8 af[8];
#pragma unroll
    for (int k = 0; k < 8; ++k)
      af[k] = ldfrag(&Wo[(size_t)(o0 + m) * CC + k * 32 + q4 * 8]);
#pragma unroll
    for (int nt4 = 0; nt4 < 2; ++nt4) {
      f32x4 a = {0.f, 0.f, 0.f, 0.f};
#pragma unroll
      for (int k = 0; k < 8; ++k) {
        bf16x8 bf = ldfrag(&As[nt4 * 16 + m][k * 32 + q4 * 8]);
        a = mfma16(af[k], bf, a);
      }
      int n = n0 + nt4 * 16 + m;
#pragma unroll
      for (int r = 0; r < 4; ++r) {
        int o = o0 + q4 * 4 + r;
        size_t idx = ((size_t)b * CC + o) * NN + n;
        out[idx] = x[idx] + bo[o] + a[r];
      }
    }
  }
}

extern "C" void kernel_launch(void* const* d_in, const int* in_sizes, int n_in,
                              void* d_out, int out_size, void* d_ws, size_t ws_size,
                              hipStream_t stream) {
  const float* x  = (const float*)d_in[0];
  const float* gw = (const float*)d_in[1];
  const float* gb = (const float*)d_in[2];
  const float* wq = (const float*)d_in[3];
  const float* bq = (const float*)d_in[4];
  const float* wk = (const float*)d_in[5];
  const float* bk = (const float*)d_in[6];
  const float* wv = (const float*)d_in[7];
  const float* bv = (const float*)d_in[8];
  const float* wo = (const float*)d_in[9];
  const float* bo = (const float*)d_in[10];

  const size_t M4 = (size_t)BB * NN * CC;
  unsigned short* xnT = (unsigned short*)d_ws;
  unsigned short* wbf = xnT + M4;                       // 4*65536 bf16
  unsigned short* accPb = wbf + 4 * CC * CC;            // KSPLIT*M4 bf16
  float* mlP  = (float*)(accPb + (size_t)KSPLIT * M4);  // KSPLIT*BBNN*2 f32
  float* part = mlP + (size_t)KSPLIT * BBNN * 2;        // 512 f32
  unsigned char* q8 = (unsigned char*)(part + 512);
  unsigned char* k8 = q8 + M4;
  unsigned char* v8 = k8 + M4;

  pre<<<512, 256, 0, stream>>>(wq, wk, wv, wo, x, wbf, part);
  gn_apply<<<512, 256, 0, stream>>>(x, gw, gb, part, xnT);
  qkv<<<768, 256, 0, stream>>>(xnT, wbf, bq, bk, bv, q8, k8, v8);
  attn<<<KSPLIT * BB * 64, 256, 0, stream>>>(q8, k8, v8, accPb, mlP);
  proj<<<512, 256, 0, stream>>>(accPb, mlP, wbf + 3 * CC * CC, bo, x, (float*)d_out);
}

// Round 10
// 260.889 us; speedup vs baseline: 1.2161x; 1.0264x over previous
//
#include <hip/hip_runtime.h>
#include <hip/hip_bf16.h>

#define BB 4
#define CC 256
#define NN 4096
#define BBNN (BB * NN)
#define NGROUPS 32
#define CPG 8
#define EPSG 1e-6f
#define QKSCL 0.30028063f             // sqrt(C^-0.5 * log2(e)) folded into q and k
#define KSPLIT 4
#define JITERS (NN / KSPLIT / 64)     // 16
#define KSTRIDE 272                   // 17 granules: padded K row (bank-spread)

typedef __bf16 bf16x8 __attribute__((ext_vector_type(8)));
typedef float  f32x4  __attribute__((ext_vector_type(4)));

typedef __attribute__((address_space(1))) const void g_void;
typedef __attribute__((address_space(3))) void l_void;

__device__ __forceinline__ unsigned short f2bf(float f) {
  unsigned u = __builtin_bit_cast(unsigned, f);
  u += 0x7fffu + ((u >> 16) & 1u);
  return (unsigned short)(u >> 16);
}
__device__ __forceinline__ float bf2f(unsigned short s) {
  return __builtin_bit_cast(float, (unsigned)s << 16);
}

__device__ __forceinline__ f32x4 mfma16(bf16x8 a, bf16x8 b, f32x4 c) {
  return __builtin_amdgcn_mfma_f32_16x16x32_bf16(a, b, c, 0, 0, 0);
}
__device__ __forceinline__ f32x4 mfma8(long a, long b, f32x4 c) {
  return __builtin_amdgcn_mfma_f32_16x16x32_fp8_fp8(a, b, c, 0, 0, 0);
}

__device__ __forceinline__ bf16x8 ldfrag(const unsigned short* p) {
  return __builtin_bit_cast(bf16x8, *(const uint4*)p);
}

// ---- fused: weights fp32->bf16 (blocks 0..255) + GroupNorm stats (256..511) ----
__global__ __launch_bounds__(256) void pre(const float* __restrict__ wq,
    const float* __restrict__ wk, const float* __restrict__ wv,
    const float* __restrict__ wo, const float* __restrict__ x,
    unsigned short* __restrict__ wbf, float* __restrict__ part) {
  if (blockIdx.x < 256) {
    int mat = blockIdx.x >> 6, blk = blockIdx.x & 63;
    const float* s = mat == 0 ? wq : mat == 1 ? wk : mat == 2 ? wv : wo;
    int i = (blk * 256 + threadIdx.x) * 4;
    float4 v = *(const float4*)&s[i];
    unsigned short* d = wbf + (size_t)mat * CC * CC + i;
    d[0] = f2bf(v.x); d[1] = f2bf(v.y); d[2] = f2bf(v.z); d[3] = f2bf(v.w);
    return;
  }
  int bx = blockIdx.x - 256;
  int pair = bx >> 1, h = bx & 1;
  const float* xp = x + (size_t)pair * (CPG * NN) + (size_t)h * (CPG * NN / 2);
  float s = 0.f, s2 = 0.f;
  for (int i = threadIdx.x; i < CPG * NN / 8; i += 256) {
    float4 v = ((const float4*)xp)[i];
    s += v.x + v.y + v.z + v.w;
    s2 += v.x * v.x + v.y * v.y + v.z * v.z + v.w * v.w;
  }
  for (int o = 32; o; o >>= 1) { s += __shfl_down(s, o); s2 += __shfl_down(s2, o); }
  __shared__ float rs[4], rs2[4];
  int wid = threadIdx.x >> 6, lane = threadIdx.x & 63;
  if (lane == 0) { rs[wid] = s; rs2[wid] = s2; }
  __syncthreads();
  if (threadIdx.x == 0) {
    part[bx * 2 + 0] = rs[0] + rs[1] + rs[2] + rs[3];
    part[bx * 2 + 1] = rs2[0] + rs2[1] + rs2[2] + rs2[3];
  }
}

// ---- fused GroupNorm + QKV: normalizes its 64-n tile from x directly,
// then projects. grid 768 = 3 modes x 4 b x 64 ntiles; low3 XCD-pins.
__global__ __launch_bounds__(256) void gqkv(const float* __restrict__ x,
    const float* __restrict__ gw, const float* __restrict__ gb,
    const float* __restrict__ part, const unsigned short* __restrict__ wbf,
    const float* __restrict__ bq, const float* __restrict__ bk,
    const float* __restrict__ bv,
    unsigned char* __restrict__ q8, unsigned char* __restrict__ k8,
    unsigned char* __restrict__ v8) {
  const int low = blockIdx.x & 7;
  const int b = low & 3, shalf = low >> 2;
  const int t = blockIdx.x >> 3;
  const int mode = t >> 5;              // 0=q, 1=k, 2=v
  const int u = t & 31;
  const int sidx = (u >> 4) * 2 + shalf;
  const int nt = sidx * 16 + (u & 15);
  const int n0 = nt * 64;
  __shared__ unsigned short Xs[64][CC + 8];
  int tid = threadIdx.x;
  const float* xb = x + (size_t)b * CC * NN;
#pragma unroll
  for (int tt = 0; tt < 2; ++tt) {       // 512 items of (8c x 4n)
    int item = tt * 256 + tid;
    int g = item >> 4, nc = item & 15;
    int pair = b * NGROUPS + g;
    float s = part[pair * 4 + 0] + part[pair * 4 + 2];
    float s2 = part[pair * 4 + 1] + part[pair * 4 + 3];
    float mean = s / (CPG * NN);
    float inv = rsqrtf(s2 / (CPG * NN) - mean * mean + EPSG);
    unsigned short row[4][8];
#pragma unroll
    for (int cc = 0; cc < 8; ++cc) {
      int c = g * 8 + cc;
      float wv = gw[c];
      float scv = inv * wv;
      float biv = gb[c] - mean * scv;
      float4 v = *(const float4*)&xb[(size_t)c * NN + n0 + nc * 4];
      row[0][cc] = f2bf(v.x * scv + biv);
      row[1][cc] = f2bf(v.y * scv + biv);
      row[2][cc] = f2bf(v.z * scv + biv);
      row[3][cc] = f2bf(v.w * scv + biv);
    }
#pragma unroll
    for (int r = 0; r < 4; ++r)
      *(uint4*)&Xs[nc * 4 + r][g * 8] = *(const uint4*)&row[r][0];
  }
  __syncthreads();
  int w = tid >> 6, lane = tid & 63;
  int m = lane & 15, q4 = lane >> 4;
  if (mode < 2) {
    bf16x8 xa[8];
#pragma unroll
    for (int k = 0; k < 8; ++k)
      xa[k] = ldfrag(&Xs[w * 16 + m][k * 32 + q4 * 8]);
    const unsigned short* W = wbf + (size_t)mode * CC * CC;
    const float* bias = mode ? bk : bq;
    unsigned char* dst = mode ? k8 : q8;
    for (int ot = 0; ot < 16; ++ot) {
      f32x4 acc = {0.f, 0.f, 0.f, 0.f};
#pragma unroll
      for (int k = 0; k < 8; ++k) {
        bf16x8 bf = ldfrag(&W[(size_t)(ot * 16 + m) * CC + k * 32 + q4 * 8]);
        acc = mfma16(xa[k], bf, acc);
      }
      int o = ot * 16 + m;
      float bia = bias[o];
      unsigned pk01 = __builtin_amdgcn_cvt_pk_fp8_f32(
          (acc[0] + bia) * QKSCL, (acc[1] + bia) * QKSCL, 0u, false);
      unsigned pk23 = __builtin_amdgcn_cvt_pk_fp8_f32(
          (acc[2] + bia) * QKSCL, (acc[3] + bia) * QKSCL, 0u, false);
      size_t base = ((size_t)b * NN + n0 + w * 16 + q4 * 4) * CC + o;
      dst[base]          = (unsigned char)(pk01 & 0xff);
      dst[base + CC]     = (unsigned char)((pk01 >> 8) & 0xff);
      dst[base + 2 * CC] = (unsigned char)(pk23 & 0xff);
      dst[base + 3 * CC] = (unsigned char)((pk23 >> 8) & 0xff);
    }
  } else {
    const unsigned short* Wv = wbf + 2 * CC * CC;
    for (int ot = 0; ot < 4; ++ot) {
      int o0 = w * 64 + ot * 16;
      bf16x8 af[8];
#pragma unroll
      for (int k = 0; k < 8; ++k)
        af[k] = ldfrag(&Wv[(size_t)(o0 + m) * CC + k * 32 + q4 * 8]);
#pragma unroll
      for (int nt4 = 0; nt4 < 4; ++nt4) {
        f32x4 acc = {0.f, 0.f, 0.f, 0.f};
#pragma unroll
        for (int k = 0; k < 8; ++k) {
          bf16x8 bfr = ldfrag(&Xs[nt4 * 16 + m][k * 32 + q4 * 8]);
          acc = mfma16(af[k], bfr, acc);
        }
        // K-dim permutation within the 64-block: j -> j''
        int j = nt4 * 16 + m;
        int jp = (j & 0x23) | ((j & 0x0C) << 1) | ((j & 0x10) >> 2);
        int n = n0 + jp;
        int o = o0 + q4 * 4;
        unsigned pk01 = __builtin_amdgcn_cvt_pk_fp8_f32(acc[0] + bv[o], acc[1] + bv[o + 1], 0u, false);
        unsigned pk23 = __builtin_amdgcn_cvt_pk_fp8_f32(acc[2] + bv[o + 2], acc[3] + bv[o + 3], 0u, false);
        size_t base = ((size_t)b * CC + o) * NN + n;
        v8[base]          = (unsigned char)(pk01 & 0xff);
        v8[base + NN]     = (unsigned char)((pk01 >> 8) & 0xff);
        v8[base + 2 * NN] = (unsigned char)(pk23 & 0xff);
        v8[base + 3 * NN] = (unsigned char)((pk23 >> 8) & 0xff);
      }
    }
  }
}

// DMA one 64-j fp8 K tile into PADDED LDS (row stride 272B = 17 granules).
// Linear source (no swizzle); pad granule loads a harmless duplicate.
__device__ __forceinline__ void stageK8(const unsigned char* __restrict__ kp,
    int j0, unsigned char* Kb, int tid) {
#pragma unroll
  for (int t = 0; t < 4; ++t) {
    int item = t * 256 + tid;
    int row = item / 17, g = item % 17;
    int gs = (g == 16) ? 0 : g;
    const unsigned char* gp = kp + (size_t)(j0 + row) * CC + gs * 16;
    __builtin_amdgcn_global_load_lds((g_void*)gp, (l_void*)(Kb + item * 16), 16, 0, 0);
  }
  if (tid < 64) {                       // wave-0-uniform tail: items 1024..1087
    int item = 1024 + tid;
    int row = item / 17, g = item % 17;
    int gs = (g == 16) ? 0 : g;
    const unsigned char* gp = kp + (size_t)(j0 + row) * CC + gs * 16;
    __builtin_amdgcn_global_load_lds((g_void*)gp, (l_void*)(Kb + item * 16), 16, 0, 0);
  }
}
// DMA one 64-j fp8 V tile (256x64B, granule XOR c&3), 256 threads.
__device__ __forceinline__ void stageV8(const unsigned char* __restrict__ vp,
    int j0, unsigned char* Vb, int tid) {
#pragma unroll
  for (int t = 0; t < 4; ++t) {
    int item = t * 256 + tid;
    int row = item >> 2, gl = item & 3;
    int gg = gl ^ (row & 3);
    const unsigned char* g = vp + (size_t)row * NN + j0 + gg * 16;
    __builtin_amdgcn_global_load_lds((g_void*)g, (l_void*)(Vb + item * 16), 16, 0, 0);
  }
}

// ---- flash attention, S^T form: grid 1024 = 16 (s,b) x 64 itiles, 256 thr ----
// K single-buffer PADDED (all QK reads = 1 base VGPR + immediate offset),
// V double-buffer XOR-swizzled. LDS 50176B -> 3 blocks/CU.
__global__ __launch_bounds__(256, 3) void attn(const unsigned char* __restrict__ q8,
    const unsigned char* __restrict__ k8, const unsigned char* __restrict__ v8,
    unsigned short* __restrict__ accP, float* __restrict__ mlP) {
  const int grp = blockIdx.x & 15;
  const int s = grp >> 2, b = grp & 3;
  const int it = blockIdx.x >> 4;
  const int i0 = it * 64;
  __shared__ __align__(16) unsigned char pool[50176];
  unsigned char* Kd  = pool;                    // 64*272 = 17408 B
  unsigned char* Vd0 = pool + 17408;            // 16384 B
  unsigned char* Vd1 = pool + 33792;            // 16384 B
  int tid = threadIdx.x, w = tid >> 6, lane = tid & 63;
  int m = lane & 15, q4 = lane >> 4;
  int q4h = q4 >> 1, q4l = q4 & 1;
  const unsigned char* kp = k8 + (size_t)b * NN * CC;
  const unsigned char* vp = v8 + (size_t)b * CC * NN;
  long qa[8];
#pragma unroll
  for (int kc = 0; kc < 8; ++kc)
    qa[kc] = *(const long*)&q8[((size_t)b * NN + i0 + w * 16 + m) * CC + kc * 32 + q4 * 8];
  f32x4 acc[16];
#pragma unroll
  for (int i = 0; i < 16; ++i) acc[i] = (f32x4){0.f, 0.f, 0.f, 0.f};
  float mrow = -1e30f, lrow = 0.f;
  const int jbase = s * (NN / KSPLIT);
  stageK8(kp, jbase, Kd, tid);
  stageV8(vp, jbase, Vd0, tid);
  const unsigned char* Kbase = Kd + m * KSTRIDE + q4 * 8;  // all QK reads: +imm
  for (int jt = 0; jt < JITERS; ++jt) {
    __syncthreads();               // A: K(jt)+V(jt) DMA drained; PV(jt-1) done
    if (jt + 1 < JITERS)
      stageV8(vp, jbase + (jt + 1) * 64, (jt & 1) ? Vd0 : Vd1, tid);
    const unsigned char* Vs = (jt & 1) ? Vd1 : Vd0;
    f32x4 sv[4];
#pragma unroll
    for (int jt4 = 0; jt4 < 4; ++jt4) {
      f32x4 a = {0.f, 0.f, 0.f, 0.f};
#pragma unroll
      for (int kc = 0; kc < 8; ++kc) {
        long kf = *(const long*)&Kbase[jt4 * 16 * KSTRIDE + kc * 32];
        a = mfma8(kf, qa[kc], a);
      }
      sv[jt4] = a;
    }
    __syncthreads();               // B: all waves done reading Kd
    if (jt + 1 < JITERS)
      stageK8(kp, jbase + (jt + 1) * 64, Kd, tid);   // overlaps softmax+PV
    float mx = fmaxf(fmaxf(fmaxf(sv[0][0], sv[0][1]), fmaxf(sv[0][2], sv[0][3])),
                     fmaxf(fmaxf(sv[1][0], sv[1][1]), fmaxf(sv[1][2], sv[1][3])));
    mx = fmaxf(mx, fmaxf(fmaxf(fmaxf(sv[2][0], sv[2][1]), fmaxf(sv[2][2], sv[2][3])),
                         fmaxf(fmaxf(sv[3][0], sv[3][1]), fmaxf(sv[3][2], sv[3][3]))));
    mx = fmaxf(mx, __shfl_xor(mx, 16));
    mx = fmaxf(mx, __shfl_xor(mx, 32));
    float mnew = fmaxf(mrow, mx);
    float alpha = exp2f(mrow - mnew);
    mrow = mnew;
    float rsum = 0.f;
    unsigned pd[4];
#pragma unroll
    for (int jt4 = 0; jt4 < 4; ++jt4) {
      float e0 = exp2f(sv[jt4][0] - mnew);
      float e1 = exp2f(sv[jt4][1] - mnew);
      float e2 = exp2f(sv[jt4][2] - mnew);
      float e3 = exp2f(sv[jt4][3] - mnew);
      rsum += (e0 + e1) + (e2 + e3);
      unsigned d = __builtin_amdgcn_cvt_pk_fp8_f32(e0, e1, 0u, false);
      pd[jt4] = __builtin_amdgcn_cvt_pk_fp8_f32(e2, e3, d, true);
    }
    rsum += __shfl_xor(rsum, 16);
    rsum += __shfl_xor(rsum, 32);
    lrow = lrow * alpha + rsum;
    if (__any(alpha != 1.0f)) {
#pragma unroll
      for (int ct = 0; ct < 16; ++ct) acc[ct] *= alpha;
    }
    int voff = ((q4h) ^ (m & 3)) * 16 + q4l * 8;          // p=0
    int voff1 = ((2 + q4h) ^ (m & 3)) * 16 + q4l * 8;     // p=1
#pragma unroll
    for (int p = 0; p < 2; ++p) {
      uint2 pu = {pd[2 * p], pd[2 * p + 1]};
      long pT = __builtin_bit_cast(long, pu);
      int vo = p ? voff1 : voff;
#pragma unroll
      for (int ct = 0; ct < 16; ++ct) {
        long vf = *(const long*)&Vs[(ct * 16 + m) * 64 + vo];
        acc[ct] = mfma8(vf, pT, acc[ct]);
      }
    }
  }
  // epilogue: per-lane (i = m) stats; O^T -> LDS transpose -> coalesced store
  size_t rq = (size_t)(s * BB + b) * NN + i0 + w * 16 + m;
  if (q4 == 0) {
    mlP[rq * 2 + 0] = mrow;
    mlP[rq * 2 + 1] = lrow;
  }
  __syncthreads();
  unsigned short* tp = (unsigned short*)pool;   // 64 rows x 260 shorts = 33.3KB
#pragma unroll
  for (int ct = 0; ct < 16; ++ct) {
    unsigned lo = f2bf(acc[ct][0]) | ((unsigned)f2bf(acc[ct][1]) << 16);
    unsigned hi = f2bf(acc[ct][2]) | ((unsigned)f2bf(acc[ct][3]) << 16);
    uint2 pk = {lo, hi};
    *(uint2*)&tp[(w * 16 + m) * 260 + ct * 16 + q4 * 4] = pk;
  }
  __syncthreads();
#pragma unroll
  for (int u = 0; u < 8; ++u) {
    int id = u * 256 + tid;
    int row = id >> 5, ck = id & 31;
    uint4 v = *(const uint4*)&tp[row * 260 + ck * 8];
    *(uint4*)&accP[((size_t)(s * BB + b) * NN + i0 + row) * CC + ck * 8] = v;
  }
}

// ---- output projection + combine partials + bias + residual; grid 512 ----
__global__ __launch_bounds__(256) void proj(const unsigned short* __restrict__ accP,
    const float* __restrict__ mlP, const unsigned short* __restrict__ Wo,
    const float* __restrict__ bo, const float* __restrict__ x,
    float* __restrict__ out) {
  const int b = blockIdx.x >> 7, nt = blockIdx.x & 127;
  const int n0 = nt * 32;
  __shared__ unsigned short As[32][CC + 8];
  __shared__ float wr[KSPLIT][36];
  int tid = threadIdx.x;
  if (tid < 32) {
    int n = n0 + tid;
    float mv[KSPLIT], lv[KSPLIT], M = -1e30f;
#pragma unroll
    for (int s = 0; s < KSPLIT; ++s) {
      size_t rq = (size_t)(s * BB + b) * NN + n;
      mv[s] = mlP[rq * 2];
      lv[s] = mlP[rq * 2 + 1];
      M = fmaxf(M, mv[s]);
    }
    float ws[KSPLIT], d = 0.f;
#pragma unroll
    for (int s = 0; s < KSPLIT; ++s) {
      ws[s] = exp2f(mv[s] - M);
      d += lv[s] * ws[s];
    }
    float inv = 1.f / d;
#pragma unroll
    for (int s = 0; s < KSPLIT; ++s) wr[s][tid] = ws[s] * inv;
  }
  __syncthreads();
#pragma unroll
  for (int i = 0; i < 4; ++i) {
    int id = tid + 256 * i;
    int r = id >> 5, ck = id & 31;
    int n = n0 + r;
    float f[8] = {0.f, 0.f, 0.f, 0.f, 0.f, 0.f, 0.f, 0.f};
#pragma unroll
    for (int s = 0; s < KSPLIT; ++s) {
      uint4 a = *(const uint4*)&accP[((size_t)(s * BB + b) * NN + n) * CC + ck * 8];
      const unsigned* p = (const unsigned*)&a;
      float wgt = wr[s][r];
#pragma unroll
      for (int k = 0; k < 4; ++k) {
        f[k * 2 + 0] += bf2f((unsigned short)(p[k] & 0xffff)) * wgt;
        f[k * 2 + 1] += bf2f((unsigned short)(p[k] >> 16)) * wgt;
      }
    }
    unsigned short ov[8];
#pragma unroll
    for (int k = 0; k < 8; ++k) ov[k] = f2bf(f[k]);
    *(uint4*)&As[r][ck * 8] = *(const uint4*)&ov[0];
  }
  __syncthreads();
  int w = tid >> 6, lane = tid & 63, m = lane & 15, q4 = lane >> 4;
  for (int ot = 0; ot < 4; ++ot) {
    int o0 = w * 64 + ot * 16;
    bf16x8 af[8];
#pragma unroll
    for (int k = 0; k < 8; ++k)
      af[k] = ldfrag(&Wo[(size_t)(o0 + m) * CC + k * 32 + q4 * 8]);
#pragma unroll
    for (int nt4 = 0; nt4 < 2; ++nt4) {
      f32x4 a = {0.f, 0.f, 0.f, 0.f};
#pragma unroll
      for (int k = 0; k < 8; ++k) {
        bf16x8 bf = ldfrag(&As[nt4 * 16 + m][k * 32 + q4 * 8]);
        a = mfma16(af[k], bf, a);
      }
      int n = n0 + nt4 * 16 + m;
#pragma unroll
      for (int r = 0; r < 4; ++r) {
        int o = o0 + q4 * 4 + r;
        size_t idx = ((size_t)b * CC + o) * NN + n;
        out[idx] = x[idx] + bo[o] + a[r];
      }
    }
  }
}

extern "C" void kernel_launch(void* const* d_in, const int* in_sizes, int n_in,
                              void* d_out, int out_size, void* d_ws, size_t ws_size,
                              hipStream_t stream) {
  const float* x  = (const float*)d_in[0];
  const float* gw = (const float*)d_in[1];
  const float* gb = (const float*)d_in[2];
  const float* wq = (const float*)d_in[3];
  const float* bq = (const float*)d_in[4];
  const float* wk = (const float*)d_in[5];
  const float* bk = (const float*)d_in[6];
  const float* wv = (const float*)d_in[7];
  const float* bv = (const float*)d_in[8];
  const float* wo = (const float*)d_in[9];
  const float* bo = (const float*)d_in[10];

  const size_t M4 = (size_t)BB * NN * CC;
  unsigned short* wbf = (unsigned short*)d_ws;          // 4*65536 bf16
  unsigned short* accPb = wbf + 4 * CC * CC;            // KSPLIT*M4 bf16
  float* mlP  = (float*)(accPb + (size_t)KSPLIT * M4);  // KSPLIT*BBNN*2 f32
  float* part = mlP + (size_t)KSPLIT * BBNN * 2;        // 512 f32
  unsigned char* q8 = (unsigned char*)(part + 512);
  unsigned char* k8 = q8 + M4;
  unsigned char* v8 = k8 + M4;

  pre<<<512, 256, 0, stream>>>(wq, wk, wv, wo, x, wbf, part);
  gqkv<<<768, 256, 0, stream>>>(x, gw, gb, part, wbf, bq, bk, bv, q8, k8, v8);
  attn<<<KSPLIT * BB * 64, 256, 0, stream>>>(q8, k8, v8, accPb, mlP);
  proj<<<512, 256, 0, stream>>>(accPb, mlP, wbf + 3 * CC * CC, bo, x, (float*)d_out);
}